// Round 1
// baseline (28.993 us; speedup 1.0000x reference)
//
#include <hip/hip_runtime.h>

// Problem constants (fixed by the reference).
constexpr int Bn = 8192;
constexpr int Kn = 256;
constexpr int Dn = 128;

constexpr int TB = 32;            // z-rows per block -> 256 blocks (1 per CU)
constexpr int KC = 128;           // clusters per LDS chunk
constexpr int NCHUNK = Kn / KC;   // 2
constexpr int LSTR = 132;         // padded LDS row stride (floats); 132*4=528B, 16B-aligned

// dist[b,k] = sum_d (z[b,d]*s[k,d] - mu[k,d]*s[k,d])^2,  s = exp(-logvar/2)
// out[b,k]  = softmax_k(-0.5*dist)

__global__ __launch_bounds__(256, 1)
void gmm_soft_kernel(const float* __restrict__ z,
                     const float* __restrict__ cent,
                     const float* __restrict__ logvar,
                     float* __restrict__ out)
{
    __shared__ float zb[TB][LSTR];    // ~16.9 KB
    __shared__ float ssb[KC][LSTR];   // ~67.6 KB
    __shared__ float msb[KC][LSTR];   // ~67.6 KB   total ~152 KB -> 1 block/CU

    const int tid = threadIdx.x;
    const int bq  = tid >> 5;   // 0..7  : which 4-row b-group
    const int kq  = tid & 31;   // 0..31 : k lane
    const long b0 = (long)blockIdx.x * TB;

    // ---- stage z tile: coalesced global float4, contiguous b128 LDS writes ----
    #pragma unroll
    for (int i = 0; i < (TB * Dn / 4) / 256; ++i) {   // 4 iters
        int idx = tid + i * 256;       // 0..1023 float4 slots
        int row = idx >> 5;            // 0..31
        int dg  = idx & 31;            // 0..31
        float4 v = *reinterpret_cast<const float4*>(z + (b0 + row) * Dn + dg * 4);
        *reinterpret_cast<float4*>(&zb[row][dg * 4]) = v;
    }

    float acc[NCHUNK][4][4];          // [chunk][bi][ki]
    #pragma unroll
    for (int c = 0; c < NCHUNK; ++c)
        #pragma unroll
        for (int bi = 0; bi < 4; ++bi)
            #pragma unroll
            for (int ki = 0; ki < 4; ++ki) acc[c][bi][ki] = 0.0f;

    for (int c = 0; c < NCHUNK; ++c) {
        __syncthreads();   // prior chunk fully consumed (and z staged, first iter)

        // ---- stage s = exp(-lv/2) and ms = mu*s for this k-chunk ----
        #pragma unroll
        for (int i = 0; i < (KC * Dn / 4) / 256; ++i) {  // 16 iters
            int idx = tid + i * 256;   // 0..4095 float4 slots
            int kl  = idx >> 5;        // 0..127
            int dg  = idx & 31;        // 0..31
            const float4 cv = *reinterpret_cast<const float4*>(cent   + (c * KC + kl) * Dn + dg * 4);
            const float4 lv = *reinterpret_cast<const float4*>(logvar + (c * KC + kl) * Dn + dg * 4);
            float4 s, m;
            s.x = __expf(-0.5f * lv.x); m.x = cv.x * s.x;
            s.y = __expf(-0.5f * lv.y); m.y = cv.y * s.y;
            s.z = __expf(-0.5f * lv.z); m.z = cv.z * s.z;
            s.w = __expf(-0.5f * lv.w); m.w = cv.w * s.w;
            *reinterpret_cast<float4*>(&ssb[kl][dg * 4]) = s;
            *reinterpret_cast<float4*>(&msb[kl][dg * 4]) = m;
        }
        __syncthreads();

        // ---- main compute: per 4-d group, 12 ds_read_b128 vs 128 FMA ----
        #pragma unroll 2
        for (int dg = 0; dg < Dn / 4; ++dg) {
            float4 z4[4];
            #pragma unroll
            for (int bi = 0; bi < 4; ++bi)
                z4[bi] = *reinterpret_cast<const float4*>(&zb[bq * 4 + bi][dg * 4]);
            #pragma unroll
            for (int ki = 0; ki < 4; ++ki) {
                const int kl = ki * 32 + kq;
                const float4 s4 = *reinterpret_cast<const float4*>(&ssb[kl][dg * 4]);
                const float4 m4 = *reinterpret_cast<const float4*>(&msb[kl][dg * 4]);
                #pragma unroll
                for (int bi = 0; bi < 4; ++bi) {
                    float t0 = fmaf(z4[bi].x, s4.x, -m4.x);
                    float t1 = fmaf(z4[bi].y, s4.y, -m4.y);
                    float t2 = fmaf(z4[bi].z, s4.z, -m4.z);
                    float t3 = fmaf(z4[bi].w, s4.w, -m4.w);
                    float a = acc[c][bi][ki];
                    a = fmaf(t0, t0, a);
                    a = fmaf(t1, t1, a);
                    a = fmaf(t2, t2, a);
                    a = fmaf(t3, t3, a);
                    acc[c][bi][ki] = a;
                }
            }
        }
    }

    // ---- softmax over k: 8 values/thread/b-row, reduce across the 32-lane half-wave ----
    #pragma unroll
    for (int bi = 0; bi < 4; ++bi) {
        float dmin = acc[0][bi][0];
        #pragma unroll
        for (int c = 0; c < NCHUNK; ++c)
            #pragma unroll
            for (int ki = 0; ki < 4; ++ki)
                dmin = fminf(dmin, acc[c][bi][ki]);
        #pragma unroll
        for (int msk = 16; msk >= 1; msk >>= 1)
            dmin = fminf(dmin, __shfl_xor(dmin, msk));

        float p[NCHUNK][4];
        float ssum = 0.0f;
        #pragma unroll
        for (int c = 0; c < NCHUNK; ++c)
            #pragma unroll
            for (int ki = 0; ki < 4; ++ki) {
                p[c][ki] = __expf(-0.5f * (acc[c][bi][ki] - dmin));
                ssum += p[c][ki];
            }
        #pragma unroll
        for (int msk = 16; msk >= 1; msk >>= 1)
            ssum += __shfl_xor(ssum, msk);

        const float inv = 1.0f / ssum;
        const long b = b0 + bq * 4 + bi;
        #pragma unroll
        for (int c = 0; c < NCHUNK; ++c)
            #pragma unroll
            for (int ki = 0; ki < 4; ++ki)
                out[b * Kn + c * KC + ki * 32 + kq] = p[c][ki] * inv;
    }
}

extern "C" void kernel_launch(void* const* d_in, const int* in_sizes, int n_in,
                              void* d_out, int out_size, void* d_ws, size_t ws_size,
                              hipStream_t stream) {
    const float* z      = (const float*)d_in[0];
    const float* cent   = (const float*)d_in[1];
    const float* logvar = (const float*)d_in[2];
    float* out = (float*)d_out;
    (void)in_sizes; (void)n_in; (void)out_size; (void)d_ws; (void)ws_size;

    dim3 grid(Bn / TB);   // 256 blocks
    dim3 block(256);
    hipLaunchKernelGGL(gmm_soft_kernel, grid, block, 0, stream, z, cent, logvar, out);
}